// Round 12
// baseline (379.786 us; speedup 1.0000x reference)
//
#include <hip/hip_runtime.h>
#include <math.h>

#define NS 65536
#define HD 256
#define NE 8

typedef short bh8 __attribute__((ext_vector_type(8)));   // 8 bf16 (A/B frag)
typedef float f4  __attribute__((ext_vector_type(4)));   // MFMA acc
typedef unsigned short ush;

// ---------------------------------------------------------------------------
// split helpers. Truncate-hi + RHU-lo: err <= 2^-17|x| (2-way), 2^-25 (3-way).
// ---------------------------------------------------------------------------
__device__ __forceinline__ void split2t(float x, ush& h, ush& l) {
    unsigned u = __float_as_uint(x);
    h = (ush)(u >> 16);
    float lo = x - __uint_as_float(u & 0xffff0000u);
    l = (ush)((__float_as_uint(lo) + 0x8000u) >> 16);
}
__device__ __forceinline__ unsigned pack2t(float x) {     // hi | lo<<16
    ush h, l; split2t(x, h, l);
    return (unsigned)h | ((unsigned)l << 16);
}
__device__ __forceinline__ float unpackf(unsigned p) {    // inverse of pack2t
    return __uint_as_float(p << 16) + __uint_as_float(p & 0xffff0000u);
}
__device__ __forceinline__ void split3t(float x, ush& h, ush& m, ush& l) {
    unsigned u = __float_as_uint(x);
    h = (ush)(u >> 16);
    float r1 = x - __uint_as_float(u & 0xffff0000u);
    unsigned u1 = __float_as_uint(r1);
    m = (ush)(u1 >> 16);
    float r2 = r1 - __uint_as_float(u1 & 0xffff0000u);
    l = (ush)((__float_as_uint(r2) + 0x8000u) >> 16);
}
// RNE splits for one-time weight preps
__device__ __forceinline__ void bfsplit(float x, ush& h, ush& l) {
    unsigned u  = __float_as_uint(x);
    unsigned hb = (u + 0x7fffu + ((u >> 16) & 1u)) & 0xffff0000u;
    h = (ush)(hb >> 16);
    float    lo = x - __uint_as_float(hb);
    unsigned ul = __float_as_uint(lo);
    l = (ush)((ul + 0x7fffu + ((ul >> 16) & 1u)) >> 16);
}
__device__ __forceinline__ void bfsplit3(float x, ush& h, ush& m, ush& l) {
    unsigned u  = __float_as_uint(x);
    unsigned hb = (u + 0x7fffu + ((u >> 16) & 1u)) & 0xffff0000u;
    h = (ush)(hb >> 16);
    float r1 = x - __uint_as_float(hb);
    unsigned u1 = __float_as_uint(r1);
    unsigned mb = (u1 + 0x7fffu + ((u1 >> 16) & 1u)) & 0xffff0000u;
    m = (ush)(mb >> 16);
    float r2 = r1 - __uint_as_float(mb);
    unsigned u2 = __float_as_uint(r2);
    l = (ush)((u2 + 0x7fffu + ((u2 >> 16) & 1u)) >> 16);
}

// 8 packed uint32 -> hi/lo bh8 planes (used once at expert gather)
__device__ __forceinline__ void unpack8(const unsigned* p, bh8& h, bh8& l) {
    uint4 a = *(const uint4*)p;
    uint4 b = *(const uint4*)(p + 4);
    union { unsigned u[4]; bh8 v; } H, L;
    H.u[0] = __builtin_amdgcn_perm(a.y, a.x, 0x05040100u);
    H.u[1] = __builtin_amdgcn_perm(a.w, a.z, 0x05040100u);
    H.u[2] = __builtin_amdgcn_perm(b.y, b.x, 0x05040100u);
    H.u[3] = __builtin_amdgcn_perm(b.w, b.z, 0x05040100u);
    L.u[0] = __builtin_amdgcn_perm(a.y, a.x, 0x07060302u);
    L.u[1] = __builtin_amdgcn_perm(a.w, a.z, 0x07060302u);
    L.u[2] = __builtin_amdgcn_perm(b.y, b.x, 0x07060302u);
    L.u[3] = __builtin_amdgcn_perm(b.w, b.z, 0x07060302u);
    h = H.v; l = L.v;
}

// ---------------------------------------------------------------------------
// 2-plane MFMA GEMM. A planes in LDS A-frag layout:
// off(row,k) = ((kc*MT + row/16)*4 + (k>>3)&3)*128 + (row&15)*8 + (k&7)
// ---------------------------------------------------------------------------
template<int KC, int NTW, int NT, int MT, int MTW>
__device__ __forceinline__ void gemm2p(const ush* __restrict__ Ah, const ush* __restrict__ Al,
                                       const ush* __restrict__ Wh, const ush* __restrict__ Wl,
                                       int lane, int mtoff, int ntoff, f4 acc[MTW][NTW])
{
    const int q = lane >> 4, m = lane & 15;
    #pragma unroll
    for (int kc = 0; kc < KC; ++kc) {
        bh8 ah[MTW], al[MTW];
        #pragma unroll
        for (int mtw = 0; mtw < MTW; ++mtw) {
            const int off = ((kc * MT + mtoff + mtw) * 4 + q) * 128 + m * 8;
            ah[mtw] = *(const bh8*)(Ah + off);
            al[mtw] = *(const bh8*)(Al + off);
        }
        #pragma unroll
        for (int nl = 0; nl < NTW; ++nl) {
            const int fo = ((kc * NT + ntoff + nl) * 64 + lane) * 8;
            const bh8 bh = *(const bh8*)(Wh + fo);
            const bh8 bl = *(const bh8*)(Wl + fo);
            #pragma unroll
            for (int mtw = 0; mtw < MTW; ++mtw) {
                acc[mtw][nl] = __builtin_amdgcn_mfma_f32_16x16x32_bf16(al[mtw], bh, acc[mtw][nl], 0, 0, 0);
                acc[mtw][nl] = __builtin_amdgcn_mfma_f32_16x16x32_bf16(ah[mtw], bl, acc[mtw][nl], 0, 0, 0);
                acc[mtw][nl] = __builtin_amdgcn_mfma_f32_16x16x32_bf16(ah[mtw], bh, acc[mtw][nl], 0, 0, 0);
            }
        }
    }
}

// 3-plane MFMA GEMM (trunk l1 only, gate-accuracy). Plane stride KC*MT*512;
// W planes stride KC*8192; NT = 16.
template<int KC, int NTW, int MT, int MTW>
__device__ __forceinline__ void gemm3(const ush* __restrict__ Ap, const ush* __restrict__ Wp,
                                      int lane, int mtoff, int ntoff, f4 acc[MTW][NTW])
{
    const int q = lane >> 4, m = lane & 15;
    const int APL = KC * MT * 512;
    const int WPL = KC * 8192;
    #pragma unroll
    for (int kc = 0; kc < KC; ++kc) {
        bh8 ah[MTW], am[MTW], al[MTW];
        #pragma unroll
        for (int mtw = 0; mtw < MTW; ++mtw) {
            const int off = ((kc * MT + mtoff + mtw) * 4 + q) * 128 + m * 8;
            ah[mtw] = *(const bh8*)(Ap + off);
            am[mtw] = *(const bh8*)(Ap + APL + off);
            al[mtw] = *(const bh8*)(Ap + 2 * APL + off);
        }
        #pragma unroll
        for (int nl = 0; nl < NTW; ++nl) {
            const int fo = ((kc * 16 + ntoff + nl) * 64 + lane) * 8;
            const bh8 bh = *(const bh8*)(Wp + fo);
            const bh8 bm = *(const bh8*)(Wp + WPL + fo);
            const bh8 bl = *(const bh8*)(Wp + 2 * WPL + fo);
            #pragma unroll
            for (int mtw = 0; mtw < MTW; ++mtw) {
                acc[mtw][nl] = __builtin_amdgcn_mfma_f32_16x16x32_bf16(ah[mtw], bl, acc[mtw][nl], 0, 0, 0);
                acc[mtw][nl] = __builtin_amdgcn_mfma_f32_16x16x32_bf16(am[mtw], bm, acc[mtw][nl], 0, 0, 0);
                acc[mtw][nl] = __builtin_amdgcn_mfma_f32_16x16x32_bf16(al[mtw], bh, acc[mtw][nl], 0, 0, 0);
                acc[mtw][nl] = __builtin_amdgcn_mfma_f32_16x16x32_bf16(ah[mtw], bm, acc[mtw][nl], 0, 0, 0);
                acc[mtw][nl] = __builtin_amdgcn_mfma_f32_16x16x32_bf16(am[mtw], bh, acc[mtw][nl], 0, 0, 0);
                acc[mtw][nl] = __builtin_amdgcn_mfma_f32_16x16x32_bf16(ah[mtw], bh, acc[mtw][nl], 0, 0, 0);
            }
        }
    }
}

// ---------------------------------------------------------------------------
// Fused weight prep: one launch does all 6 preps + counts zeroing.
// Block segments: [0,1024) expert | [1024,1040) Ws1 | [1040,1058) Wc1 |
// [1058,1066) W1(3pl) | [1066,1098) W2(2pl) | [1098,1106) gate | 1106 counts.
// ---------------------------------------------------------------------------
__global__ void prep_all(const float* __restrict__ We, ush* __restrict__ EWp,
                         const float* __restrict__ Ws1, ush* __restrict__ Ws1p,
                         const float* __restrict__ Wc1, ush* __restrict__ Wc1p,
                         const float* __restrict__ W1, ush* __restrict__ W1p,
                         const float* __restrict__ W2, ush* __restrict__ W2p2,
                         const float* __restrict__ b2,
                         const float* __restrict__ Wg, const float* __restrict__ bg,
                         float* __restrict__ Wg2, float* __restrict__ bg2,
                         int* __restrict__ counts)
{
    const int blk = blockIdx.x;
    if (blk < 1024) {                       // expert weights, 2-plane
        const int gid = blk * 256 + threadIdx.x;
        const int nn = gid & 15, nt = (gid >> 4) & 15, qd = (gid >> 8) & 3;
        const int kc = (gid >> 10) & 7, el = gid >> 13;
        const int n = nt * 16 + nn;
        const float* src = We + (size_t)el * 65536 + (size_t)(kc * 32 + qd * 8) * 256 + n;
        union { ush u[8]; bh8 v; } H, L;
        #pragma unroll
        for (int j = 0; j < 8; ++j) bfsplit(src[j * 256], H.u[j], L.u[j]);
        ush* d = EWp + (size_t)el * 131072 + (size_t)((kc * 16 + nt) * 64 + qd * 16 + nn) * 8;
        *(bh8*)d = H.v;
        *(bh8*)(d + 65536) = L.v;
    } else if (blk < 1058) {                // head weights, 2-plane
        const int isC = blk >= 1040;
        const int gid = (isC ? blk - 1040 : blk - 1024) * 256 + threadIdx.x;
        const int KC = isC ? 9 : 8, Kreal = isC ? 283 : 256;
        if (gid >= KC * 512) return;
        const float* W = isC ? Wc1 : Ws1;
        ush* dst = isC ? Wc1p : Ws1p;
        const int nn = gid & 15, nt = (gid >> 4) & 7, qd = (gid >> 7) & 3, kc = gid >> 9;
        const int n = nt * 16 + nn;
        union { ush u[8]; bh8 v; } H, L;
        #pragma unroll
        for (int j = 0; j < 8; ++j) {
            const int k = kc * 32 + qd * 8 + j;
            const float x = (k < Kreal) ? W[k * 128 + n] : 0.f;
            bfsplit(x, H.u[j], L.u[j]);
        }
        ush* d = dst + (size_t)((kc * 8 + nt) * 64 + qd * 16 + nn) * 8;
        *(bh8*)d = H.v;
        *(bh8*)(d + KC * 4096) = L.v;
    } else if (blk < 1066) {                // trunk W1, 3-plane
        const int gid = (blk - 1058) * 256 + threadIdx.x;
        const int KC = 2, Kreal = 63;
        const int n15 = gid & 15, qd = (gid >> 4) & 3, nt = (gid >> 6) & 15, kc = gid >> 10;
        const int n = nt * 16 + n15;
        const int plane = KC * 8192;
        union { ush u[8]; bh8 v; } H, M, L;
        #pragma unroll
        for (int j = 0; j < 8; ++j) {
            const int k = kc * 32 + qd * 8 + j;
            const float x = (k < Kreal) ? W1[k * 256 + n] : 0.f;
            bfsplit3(x, H.u[j], M.u[j], L.u[j]);
        }
        ush* d = W1p + (size_t)gid * 8;
        *(bh8*)d = H.v;
        *(bh8*)(d + plane) = M.v;
        *(bh8*)(d + 2 * plane) = L.v;
    } else if (blk < 1098) {                // trunk W2, 2-plane
        const int gid = (blk - 1066) * 256 + threadIdx.x;
        const int KC = 8;
        const int n15 = gid & 15, qd = (gid >> 4) & 3, nt = (gid >> 6) & 15, kc = gid >> 10;
        const int n = nt * 16 + n15;
        const int plane = KC * 8192;
        union { ush u[8]; bh8 v; } H, L;
        #pragma unroll
        for (int j = 0; j < 8; ++j) {
            const int k = kc * 32 + qd * 8 + j;
            bfsplit(W2[k * 256 + n], H.u[j], L.u[j]);
        }
        ush* d = W2p2 + (size_t)gid * 8;
        *(bh8*)d = H.v;
        *(bh8*)(d + plane) = L.v;
    } else if (blk < 1106) {                // fused gate: Wg2 = W2@Wg, bg2
        const int gid = (blk - 1098) * 256 + threadIdx.x;
        const int k = gid >> 3, e = gid & 7;
        float s = 0.f;
        for (int j = 0; j < HD; ++j) s += W2[k * HD + j] * Wg[j * NE + e];
        Wg2[k * NE + e] = s;
        if (gid < NE) {
            float t = bg[gid];
            for (int j = 0; j < HD; ++j) t += b2[j] * Wg[j * NE + gid];
            bg2[gid] = t;
        }
    } else {                                // counts zeroing
        if (threadIdx.x < NE) counts[threadIdx.x] = 0;
    }
}

// ---------------------------------------------------------------------------
// Kernel 1: posenc -> l1 (3-plane 6-term) -> l2 (2-plane 3-term) -> fused gate
// + bucket. 32 rows/block, 512 thr (8 waves all-M, NTW=2). 2 blocks/CU.
// (unchanged from proven R8/R11 config)
// ---------------------------------------------------------------------------
__global__ __launch_bounds__(512, 4) void trunk_kernel(
    const float* __restrict__ xyz,
    const ush* __restrict__ W1p, const float* __restrict__ b1,
    const ush* __restrict__ W2p2, const float* __restrict__ b2,
    const float* __restrict__ Wg2, const float* __restrict__ bg2,
    unsigned* __restrict__ h2p, float* __restrict__ gateout,
    int* __restrict__ counts, int* __restrict__ bucket)
{
    __shared__ ush   exP[3 * 2048];   // posenc 3 planes (KC=2, MT=2); later gate partials
    __shared__ ush   h1h[8192];       // h1 hi plane (KC=8, MT=2)
    __shared__ ush   h1l[8192];       // h1 lo plane
    __shared__ float h1f[32 * 259];   // h1 fp32 (gate path)
    __shared__ int   lcount[NE], lbase[NE], lpos[32], lexp[32];

    const int tid  = threadIdx.x;
    const int row0 = blockIdx.x * 32;
    if (tid < NE) lcount[tid] = 0;

    {   // posenc: thread (row, g) writes 4 k's
        const int row = tid & 31, g = tid >> 5;
        const int i = row0 + row;
        const float xv[3] = {xyz[3 * i], xyz[3 * i + 1], xyz[3 * i + 2]};
        const int mt = row >> 4, m = row & 15;
        #pragma unroll
        for (int kk = 0; kk < 4; ++kk) {
            const int k = g * 4 + kk;
            float v = 0.f;
            if (k < 3) v = xv[k];
            else if (k < 63) {
                const int l = (k - 3) / 6, c = (k - 3) % 6;
                const float f = (float)(1 << l);
                v = (c < 3) ? sinf(f * xv[c]) : cosf(f * xv[c - 3]);
            }
            const int kc = k >> 5, qq = (k >> 3) & 3, j = k & 7;
            const int off = ((kc * 2 + mt) * 4 + qq) * 128 + m * 8 + j;
            ush hh, mm, ll; split3t(v, hh, mm, ll);
            exP[off] = hh; exP[2048 + off] = mm; exP[4096 + off] = ll;
        }
    }
    __syncthreads();

    const int lane = tid & 63, wv = tid >> 6;
    const int q = lane >> 4, n15 = lane & 15;

    // --- l1 = relu(ex @ W1 + b1): 6-term; store fp32 (gate) + 2-plane (l2) ---
    {
        f4 acc[2][2];
        #pragma unroll
        for (int a = 0; a < 2; ++a)
            #pragma unroll
            for (int b_ = 0; b_ < 2; ++b_) acc[a][b_] = (f4){0.f, 0.f, 0.f, 0.f};
        gemm3<2, 2, 2, 2>(exP, W1p, lane, 0, wv * 2, acc);
        #pragma unroll
        for (int nl = 0; nl < 2; ++nl) {
            const int col = wv * 32 + nl * 16 + n15;
            const float bias = b1[col];
            const int kc = col >> 5, qc = (col >> 3) & 3, jc = col & 7;
            #pragma unroll
            for (int mt = 0; mt < 2; ++mt)
                #pragma unroll
                for (int r = 0; r < 4; ++r) {
                    const int row = mt * 16 + q * 4 + r;
                    const float v = fmaxf(acc[mt][nl][r] + bias, 0.f);
                    const int off = ((kc * 2 + mt) * 4 + qc) * 128 + (q * 4 + r) * 8 + jc;
                    ush hh, ll; split2t(v, hh, ll);
                    h1h[off] = hh; h1l[off] = ll;
                    h1f[row * 259 + col] = v;
                }
        }
    }
    __syncthreads();

    // --- l2 = h1 @ W2 + b2: 2-plane 3-term; epilogue straight to global ---
    {
        f4 acc[2][2];
        #pragma unroll
        for (int a = 0; a < 2; ++a)
            #pragma unroll
            for (int b_ = 0; b_ < 2; ++b_) acc[a][b_] = (f4){0.f, 0.f, 0.f, 0.f};
        gemm2p<8, 2, 16, 2, 2>(h1h, h1l, W2p2, W2p2 + 65536, lane, 0, wv * 2, acc);
        __syncthreads();   // all h1h/h1l reads done before part overlay
        #pragma unroll
        for (int nl = 0; nl < 2; ++nl) {
            const int col = wv * 32 + nl * 16 + n15;
            const float bias = b2[col];
            #pragma unroll
            for (int mt = 0; mt < 2; ++mt)
                #pragma unroll
                for (int r = 0; r < 4; ++r) {
                    const int row = mt * 16 + q * 4 + r;
                    h2p[(size_t)(row0 + row) * HD + col] = pack2t(acc[mt][nl][r] + bias);
                }
        }
    }

    // --- gate partials from h1f via fused Wg2 (h1f stable; exP dead) ---
    float* part = (float*)exP;        // [8][32][8]
    if (tid < 256) {
        const int row = tid & 31, seg = tid >> 5, k0 = seg * 32;
        float lg[NE];
        #pragma unroll
        for (int e = 0; e < NE; ++e) lg[e] = 0.f;
        for (int k = k0; k < k0 + 32; ++k) {
            const float hv = h1f[row * 259 + k];
            const float4 w0 = *(const float4*)(Wg2 + k * 8);
            const float4 w1 = *(const float4*)(Wg2 + k * 8 + 4);
            lg[0] = fmaf(hv, w0.x, lg[0]); lg[1] = fmaf(hv, w0.y, lg[1]);
            lg[2] = fmaf(hv, w0.z, lg[2]); lg[3] = fmaf(hv, w0.w, lg[3]);
            lg[4] = fmaf(hv, w1.x, lg[4]); lg[5] = fmaf(hv, w1.y, lg[5]);
            lg[6] = fmaf(hv, w1.z, lg[6]); lg[7] = fmaf(hv, w1.w, lg[7]);
        }
        #pragma unroll
        for (int e = 0; e < NE; ++e) part[(seg * 32 + row) * 8 + e] = lg[e];
    }
    __syncthreads();

    if (tid < 32) {
        float lg[NE];
        #pragma unroll
        for (int e = 0; e < NE; ++e) {
            float s = bg2[e];
            #pragma unroll
            for (int sg = 0; sg < 8; ++sg) s += part[(sg * 32 + tid) * 8 + e];
            lg[e] = s;
        }
        int best = 0; float mx = lg[0];
        #pragma unroll
        for (int e = 1; e < NE; ++e) if (lg[e] > mx) { mx = lg[e]; best = e; }
        float s = 0.f;
        #pragma unroll
        for (int e = 0; e < NE; ++e) s += expf(lg[e] - mx);
        gateout[row0 + tid] = 1.f / s;
        lexp[tid] = best;
        lpos[tid] = atomicAdd(&lcount[best], 1);
    }
    __syncthreads();
    if (tid < NE) lbase[tid] = atomicAdd(&counts[tid], lcount[tid]);
    __syncthreads();
    if (tid < 32) {
        const int e = lexp[tid];
        bucket[e * NS + lbase[e] + lpos[tid]] = row0 + tid;
    }
}

// ---------------------------------------------------------------------------
// Kernel 2: expert MLP + heads. 128 rows/block, 512 threads = 8 waves all-M
// (MT=8) x NTW=2; B loaded once per block. LDS ~153KB -> 1 block/CU with a
// 256-VGPR budget (launch_bounds(512,2)): halved barrier events + B traffic
// per CU, deep register prefetch headroom.
// ---------------------------------------------------------------------------
__global__ __launch_bounds__(512, 2) void expert_kernel(
    const unsigned* __restrict__ h2p, const float* __restrict__ gatebuf,
    const int* __restrict__ counts, const int* __restrict__ bucket,
    const ush* __restrict__ EWp, const float* __restrict__ be,
    const float* __restrict__ dirs,
    const ush* __restrict__ Ws1p, const float* __restrict__ bs1,
    const float* __restrict__ Ws2, const float* __restrict__ bs2,
    const ush* __restrict__ Wc1p, const float* __restrict__ bc1,
    const float* __restrict__ Wc2, const float* __restrict__ bc2,
    float* __restrict__ outp)
{
    __shared__ ush   Ah[9 * 4096];      // hi plane (KC=9, MT=8); later fp32 s [128][133]
    __shared__ ush   Al[9 * 4096];      // lo plane;               later fp32 c
    __shared__ float dotp[4 * 128 * 4];
    __shared__ int   idx[128];
    __shared__ float gatev[128];

    const int tid = threadIdx.x;
    const int e   = blockIdx.x >> 9;
    const int t   = blockIdx.x & 511;
    const int cnt = counts[e];
    if (t * 128 >= cnt) return;
    const int nact = min(128, cnt - t * 128);

    if (tid < 128) {
        const int src = bucket[e * NS + t * 128 + min(tid, nact - 1)];
        idx[tid]   = src;
        gatev[tid] = gatebuf[src];
    }
    __syncthreads();

    const int lane = tid & 63, wv = tid >> 6;
    const int q = lane >> 4, n15 = lane & 15;

    {   // gather: wave wv -> kc=wv; each lane handles rows (lane, lane+64)
        #pragma unroll
        for (int half = 0; half < 2; ++half) {
            const int row = lane + half * 64, mt = row >> 4, m = row & 15;
            const unsigned* src = h2p + (size_t)idx[row] * HD + wv * 32;
            #pragma unroll
            for (int sub = 0; sub < 4; ++sub) {
                bh8 hv, lv;
                unpack8(src + sub * 8, hv, lv);
                const int off = ((wv * 8 + mt) * 4 + sub) * 128 + m * 8;
                *(bh8*)(Ah + off) = hv;
                *(bh8*)(Al + off) = lv;
            }
        }
    }
    if (tid < 128) {   // dirs posenc ext -> kc=8 region
        const int row = tid, i = idx[row];
        const int mt = row >> 4, m = row & 15;
        const float d0 = dirs[3 * i], d1 = dirs[3 * i + 1], d2 = dirs[3 * i + 2];
        float vals[32];
        vals[0] = d0; vals[1] = d1; vals[2] = d2;
        float f = 1.f;
        #pragma unroll
        for (int l = 0; l < 4; ++l) {
            vals[3 + 6 * l + 0] = sinf(f * d0);
            vals[3 + 6 * l + 1] = sinf(f * d1);
            vals[3 + 6 * l + 2] = sinf(f * d2);
            vals[3 + 6 * l + 3] = cosf(f * d0);
            vals[3 + 6 * l + 4] = cosf(f * d1);
            vals[3 + 6 * l + 5] = cosf(f * d2);
            f *= 2.f;
        }
        #pragma unroll
        for (int c = 27; c < 32; ++c) vals[c] = 0.f;
        #pragma unroll
        for (int k2 = 0; k2 < 32; ++k2) {
            const int off = ((8 * 8 + mt) * 4 + (k2 >> 3)) * 128 + m * 8 + (k2 & 7);
            ush hh, ll; split2t(vals[k2], hh, ll);
            Ah[off] = hh; Al[off] = ll;
        }
    }
    __syncthreads();

    const float* bb = be + e * 4 * HD;
    const ush* W0 = EWp + (size_t)(e * 4) * 131072;

    // ---- l0: A <- relu(A @ W0 + b0) ----
    {
        f4 acc[8][2];
        #pragma unroll
        for (int mt = 0; mt < 8; ++mt)
            #pragma unroll
            for (int nl = 0; nl < 2; ++nl) acc[mt][nl] = (f4){0.f, 0.f, 0.f, 0.f};
        gemm2p<8, 2, 16, 8, 8>(Ah, Al, W0, W0 + 65536, lane, 0, wv * 2, acc);
        __syncthreads();
        #pragma unroll
        for (int nl = 0; nl < 2; ++nl) {
            const int col = wv * 32 + nl * 16 + n15;
            const float bias = bb[col];
            const int kc = col >> 5, qc = (col >> 3) & 3, jc = col & 7;
            #pragma unroll
            for (int mt = 0; mt < 8; ++mt)
                #pragma unroll
                for (int r = 0; r < 4; ++r) {
                    const int off = ((kc * 8 + mt) * 4 + qc) * 128 + (q * 4 + r) * 8 + jc;
                    const float v = fmaxf(acc[mt][nl][r] + bias, 0.f);
                    ush hh, ll; split2t(v, hh, ll);
                    Ah[off] = hh; Al[off] = ll;
                }
        }
        __syncthreads();
    }
    // ---- l1: A <- relu(A @ W1 + b1 + skip)   (skip re-read from L2-hot h2p) ----
    {
        f4 acc[8][2];
        #pragma unroll
        for (int mt = 0; mt < 8; ++mt)
            #pragma unroll
            for (int nl = 0; nl < 2; ++nl) acc[mt][nl] = (f4){0.f, 0.f, 0.f, 0.f};
        gemm2p<8, 2, 16, 8, 8>(Ah, Al, W0 + 131072, W0 + 131072 + 65536, lane, 0, wv * 2, acc);
        __syncthreads();
        #pragma unroll
        for (int nl = 0; nl < 2; ++nl) {
            const int col = wv * 32 + nl * 16 + n15;
            const float bias = bb[256 + col];
            const int kc = col >> 5, qc = (col >> 3) & 3, jc = col & 7;
            #pragma unroll
            for (int mt = 0; mt < 8; ++mt)
                #pragma unroll
                for (int r = 0; r < 4; ++r) {
                    const int row = mt * 16 + q * 4 + r;
                    const int off = ((kc * 8 + mt) * 4 + qc) * 128 + (q * 4 + r) * 8 + jc;
                    const float sk = unpackf(h2p[(size_t)idx[row] * HD + col]);
                    const float v = fmaxf(acc[mt][nl][r] + bias + sk, 0.f);
                    ush hh, ll; split2t(v, hh, ll);
                    Ah[off] = hh; Al[off] = ll;
                }
        }
        __syncthreads();
    }
    // ---- l2: A <- relu(A @ W2 + b2) ----
    {
        f4 acc[8][2];
        #pragma unroll
        for (int mt = 0; mt < 8; ++mt)
            #pragma unroll
            for (int nl = 0; nl < 2; ++nl) acc[mt][nl] = (f4){0.f, 0.f, 0.f, 0.f};
        gemm2p<8, 2, 16, 8, 8>(Ah, Al, W0 + 2 * 131072, W0 + 2 * 131072 + 65536, lane, 0, wv * 2, acc);
        __syncthreads();
        #pragma unroll
        for (int nl = 0; nl < 2; ++nl) {
            const int col = wv * 32 + nl * 16 + n15;
            const float bias = bb[512 + col];
            const int kc = col >> 5, qc = (col >> 3) & 3, jc = col & 7;
            #pragma unroll
            for (int mt = 0; mt < 8; ++mt)
                #pragma unroll
                for (int r = 0; r < 4; ++r) {
                    const int off = ((kc * 8 + mt) * 4 + qc) * 128 + (q * 4 + r) * 8 + jc;
                    const float v = fmaxf(acc[mt][nl][r] + bias, 0.f);
                    ush hh, ll; split2t(v, hh, ll);
                    Ah[off] = hh; Al[off] = ll;
                }
        }
        __syncthreads();
    }
    // ---- l3: A <- gate * (A @ W3 + b3)  (no relu) ----
    {
        f4 acc[8][2];
        #pragma unroll
        for (int mt = 0; mt < 8; ++mt)
            #pragma unroll
            for (int nl = 0; nl < 2; ++nl) acc[mt][nl] = (f4){0.f, 0.f, 0.f, 0.f};
        gemm2p<8, 2, 16, 8, 8>(Ah, Al, W0 + 3 * 131072, W0 + 3 * 131072 + 65536, lane, 0, wv * 2, acc);
        __syncthreads();
        #pragma unroll
        for (int nl = 0; nl < 2; ++nl) {
            const int col = wv * 32 + nl * 16 + n15;
            const float bias = bb[768 + col];
            const int kc = col >> 5, qc = (col >> 3) & 3, jc = col & 7;
            #pragma unroll
            for (int mt = 0; mt < 8; ++mt)
                #pragma unroll
                for (int r = 0; r < 4; ++r) {
                    const int row = mt * 16 + q * 4 + r;
                    const int off = ((kc * 8 + mt) * 4 + qc) * 128 + (q * 4 + r) * 8 + jc;
                    const float v = gatev[row] * (acc[mt][nl][r] + bias);
                    ush hh, ll; split2t(v, hh, ll);
                    Ah[off] = hh; Al[off] = ll;
                }
        }
        __syncthreads();
    }

    // ---- heads: s = relu(out@Ws1+bs1), c = relu([out,ed]@Wc1+bc1) ----
    {
        f4 sacc[8][1], cacc[8][1];
        #pragma unroll
        for (int mt = 0; mt < 8; ++mt) {
            sacc[mt][0] = (f4){0.f, 0.f, 0.f, 0.f};
            cacc[mt][0] = (f4){0.f, 0.f, 0.f, 0.f};
        }
        gemm2p<8, 1, 8, 8, 8>(Ah, Al, Ws1p, Ws1p + 32768, lane, 0, wv, sacc);
        gemm2p<9, 1, 8, 8, 8>(Ah, Al, Wc1p, Wc1p + 36864, lane, 0, wv, cacc);
        __syncthreads();
        float* sp = (float*)Ah;          // [128][133]
        float* cp = (float*)Al;
        const int col = wv * 16 + n15;
        const float b_s = bs1[col], b_c = bc1[col];
        #pragma unroll
        for (int mt = 0; mt < 8; ++mt)
            #pragma unroll
            for (int r = 0; r < 4; ++r) {
                const int row = mt * 16 + q * 4 + r;
                sp[row * 133 + col] = fmaxf(sacc[mt][0][r] + b_s, 0.f);
                cp[row * 133 + col] = fmaxf(cacc[mt][0][r] + b_c, 0.f);
            }
        __syncthreads();
    }
    // ---- final dots: 4 segs x 128 rows (all 512 threads), 32 k each ----
    {
        const float* sp = (const float*)Ah;
        const float* cp = (const float*)Al;
        const int row = tid & 127, seg = tid >> 7, k0 = seg * 32;
        float ps = 0.f, p0 = 0.f, p1 = 0.f, p2 = 0.f;
        for (int k = k0; k < k0 + 32; ++k) {
            ps = fmaf(sp[row * 133 + k], Ws2[k], ps);
            const float cv = cp[row * 133 + k];
            p0 = fmaf(cv, Wc2[3 * k + 0], p0);
            p1 = fmaf(cv, Wc2[3 * k + 1], p1);
            p2 = fmaf(cv, Wc2[3 * k + 2], p2);
        }
        *(float4*)&dotp[(seg * 128 + row) * 4] = make_float4(ps, p0, p1, p2);
    }
    __syncthreads();
    if (tid < nact) {
        float sg = bs2[0], r0 = bc2[0], r1 = bc2[1], r2 = bc2[2];
        #pragma unroll
        for (int s2 = 0; s2 < 4; ++s2) {
            const float4 pv = *(const float4*)&dotp[(s2 * 128 + tid) * 4];
            sg += pv.x; r0 += pv.y; r1 += pv.z; r2 += pv.w;
        }
        float4 o;
        o.x = 1.f / (1.f + expf(-r0));
        o.y = 1.f / (1.f + expf(-r1));
        o.z = 1.f / (1.f + expf(-r2));
        o.w = fmaxf(sg, 0.f) + log1pf(expf(-fabsf(sg)));
        *(float4*)&outp[(size_t)idx[tid] * 4] = o;
    }
}

// ---------------------------------------------------------------------------
extern "C" void kernel_launch(void* const* d_in, const int* in_sizes, int n_in,
                              void* d_out, int out_size, void* d_ws, size_t ws_size,
                              hipStream_t stream)
{
    const float* xyz  = (const float*)d_in[0];
    const float* dirs = (const float*)d_in[1];
    const float* W1   = (const float*)d_in[2];
    const float* b1   = (const float*)d_in[3];
    const float* W2   = (const float*)d_in[4];
    const float* b2   = (const float*)d_in[5];
    const float* Wg   = (const float*)d_in[6];
    const float* bg   = (const float*)d_in[7];
    const float* We   = (const float*)d_in[8];
    const float* be   = (const float*)d_in[9];
    const float* Ws1  = (const float*)d_in[10];
    const float* bs1  = (const float*)d_in[11];
    const float* Ws2  = (const float*)d_in[12];
    const float* bs2  = (const float*)d_in[13];
    const float* Wc1  = (const float*)d_in[14];
    const float* bc1  = (const float*)d_in[15];
    const float* Wc2  = (const float*)d_in[16];
    const float* bc2  = (const float*)d_in[17];
    float* out = (float*)d_out;

    char* ws = (char*)d_ws;
    unsigned* h2p     = (unsigned*)ws;                        // 64 MB packed h2
    float*    gatebuf = (float*)(ws + 67108864);              // 256 KB
    int*      counts  = (int*)(ws + 67371008);                // 1 KB (padded)
    int*      bucket  = (int*)(ws + 67372032);                // 2 MB
    ush*      EWp     = (ush*)(ws + 69469184);                // 8 MB expert frags
    ush*      Ws1p    = (ush*)(ws + 77857792);                // 128 KB
    ush*      Wc1p    = (ush*)(ws + 77988864);                // 144 KB
    ush*      W1p     = (ush*)(ws + 78136320);                // 96 KB  (3 planes)
    ush*      W2p2    = (ush*)(ws + 78234624);                // 256 KB (2 planes)
    float*    Wg2     = (float*)(ws + 78496768);              // 8 KB
    float*    bg2     = (float*)(ws + 78504960);              // 32 B

    prep_all<<<1107, 256, 0, stream>>>(We, EWp, Ws1, Ws1p, Wc1, Wc1p,
                                       W1, W1p, W2, W2p2, b2, Wg, bg,
                                       Wg2, bg2, counts);
    trunk_kernel<<<NS / 32, 512, 0, stream>>>(xyz, W1p, b1, W2p2, b2, Wg2, bg2,
                                              h2p, gatebuf, counts, bucket);
    expert_kernel<<<NE * 512, 512, 0, stream>>>(h2p, gatebuf, counts, bucket,
                                                EWp, be, dirs, Ws1p, bs1, Ws2, bs2,
                                                Wc1p, bc1, Wc2, bc2, out);
}

// Round 13
// 328.029 us; speedup vs baseline: 1.1578x; 1.1578x over previous
//
#include <hip/hip_runtime.h>
#include <math.h>

#define NS 65536
#define HD 256
#define NE 8

typedef short bh8 __attribute__((ext_vector_type(8)));   // 8 bf16 (A/B frag)
typedef float f4  __attribute__((ext_vector_type(4)));   // MFMA acc
typedef unsigned short ush;

// ---------------------------------------------------------------------------
// split helpers. Truncate-hi + RHU-lo: err <= 2^-17|x| (2-way), 2^-25 (3-way).
// ---------------------------------------------------------------------------
__device__ __forceinline__ void split2t(float x, ush& h, ush& l) {
    unsigned u = __float_as_uint(x);
    h = (ush)(u >> 16);
    float lo = x - __uint_as_float(u & 0xffff0000u);
    l = (ush)((__float_as_uint(lo) + 0x8000u) >> 16);
}
__device__ __forceinline__ unsigned pack2t(float x) {     // hi | lo<<16
    ush h, l; split2t(x, h, l);
    return (unsigned)h | ((unsigned)l << 16);
}
__device__ __forceinline__ float unpackf(unsigned p) {    // inverse of pack2t
    return __uint_as_float(p << 16) + __uint_as_float(p & 0xffff0000u);
}
__device__ __forceinline__ void split3t(float x, ush& h, ush& m, ush& l) {
    unsigned u = __float_as_uint(x);
    h = (ush)(u >> 16);
    float r1 = x - __uint_as_float(u & 0xffff0000u);
    unsigned u1 = __float_as_uint(r1);
    m = (ush)(u1 >> 16);
    float r2 = r1 - __uint_as_float(u1 & 0xffff0000u);
    l = (ush)((__float_as_uint(r2) + 0x8000u) >> 16);
}
// RNE splits for one-time weight preps
__device__ __forceinline__ void bfsplit(float x, ush& h, ush& l) {
    unsigned u  = __float_as_uint(x);
    unsigned hb = (u + 0x7fffu + ((u >> 16) & 1u)) & 0xffff0000u;
    h = (ush)(hb >> 16);
    float    lo = x - __uint_as_float(hb);
    unsigned ul = __float_as_uint(lo);
    l = (ush)((ul + 0x7fffu + ((ul >> 16) & 1u)) >> 16);
}
__device__ __forceinline__ void bfsplit3(float x, ush& h, ush& m, ush& l) {
    unsigned u  = __float_as_uint(x);
    unsigned hb = (u + 0x7fffu + ((u >> 16) & 1u)) & 0xffff0000u;
    h = (ush)(hb >> 16);
    float r1 = x - __uint_as_float(hb);
    unsigned u1 = __float_as_uint(r1);
    unsigned mb = (u1 + 0x7fffu + ((u1 >> 16) & 1u)) & 0xffff0000u;
    m = (ush)(mb >> 16);
    float r2 = r1 - __uint_as_float(mb);
    unsigned u2 = __float_as_uint(r2);
    l = (ush)((u2 + 0x7fffu + ((u2 >> 16) & 1u)) >> 16);
}

// 8 packed uint32 -> hi/lo bh8 planes (used once at expert gather)
__device__ __forceinline__ void unpack8(const unsigned* p, bh8& h, bh8& l) {
    uint4 a = *(const uint4*)p;
    uint4 b = *(const uint4*)(p + 4);
    union { unsigned u[4]; bh8 v; } H, L;
    H.u[0] = __builtin_amdgcn_perm(a.y, a.x, 0x05040100u);
    H.u[1] = __builtin_amdgcn_perm(a.w, a.z, 0x05040100u);
    H.u[2] = __builtin_amdgcn_perm(b.y, b.x, 0x05040100u);
    H.u[3] = __builtin_amdgcn_perm(b.w, b.z, 0x05040100u);
    L.u[0] = __builtin_amdgcn_perm(a.y, a.x, 0x07060302u);
    L.u[1] = __builtin_amdgcn_perm(a.w, a.z, 0x07060302u);
    L.u[2] = __builtin_amdgcn_perm(b.y, b.x, 0x07060302u);
    L.u[3] = __builtin_amdgcn_perm(b.w, b.z, 0x07060302u);
    h = H.v; l = L.v;
}

// ---------------------------------------------------------------------------
// 2-plane MFMA GEMM. A planes in LDS A-frag layout:
// off(row,k) = ((kc*MT + row/16)*4 + (k>>3)&3)*128 + (row&15)*8 + (k&7)
// ---------------------------------------------------------------------------
template<int KC, int NTW, int NT, int MT, int MTW>
__device__ __forceinline__ void gemm2p(const ush* __restrict__ Ah, const ush* __restrict__ Al,
                                       const ush* __restrict__ Wh, const ush* __restrict__ Wl,
                                       int lane, int mtoff, int ntoff, f4 acc[MTW][NTW])
{
    const int q = lane >> 4, m = lane & 15;
    #pragma unroll
    for (int kc = 0; kc < KC; ++kc) {
        bh8 ah[MTW], al[MTW];
        #pragma unroll
        for (int mtw = 0; mtw < MTW; ++mtw) {
            const int off = ((kc * MT + mtoff + mtw) * 4 + q) * 128 + m * 8;
            ah[mtw] = *(const bh8*)(Ah + off);
            al[mtw] = *(const bh8*)(Al + off);
        }
        #pragma unroll
        for (int nl = 0; nl < NTW; ++nl) {
            const int fo = ((kc * NT + ntoff + nl) * 64 + lane) * 8;
            const bh8 bh = *(const bh8*)(Wh + fo);
            const bh8 bl = *(const bh8*)(Wl + fo);
            #pragma unroll
            for (int mtw = 0; mtw < MTW; ++mtw) {
                acc[mtw][nl] = __builtin_amdgcn_mfma_f32_16x16x32_bf16(al[mtw], bh, acc[mtw][nl], 0, 0, 0);
                acc[mtw][nl] = __builtin_amdgcn_mfma_f32_16x16x32_bf16(ah[mtw], bl, acc[mtw][nl], 0, 0, 0);
                acc[mtw][nl] = __builtin_amdgcn_mfma_f32_16x16x32_bf16(ah[mtw], bh, acc[mtw][nl], 0, 0, 0);
            }
        }
    }
}

// 3-plane MFMA GEMM (trunk l1 only, gate-accuracy). Plane stride KC*MT*512;
// W planes stride KC*8192; NT = 16.
template<int KC, int NTW, int MT, int MTW>
__device__ __forceinline__ void gemm3(const ush* __restrict__ Ap, const ush* __restrict__ Wp,
                                      int lane, int mtoff, int ntoff, f4 acc[MTW][NTW])
{
    const int q = lane >> 4, m = lane & 15;
    const int APL = KC * MT * 512;
    const int WPL = KC * 8192;
    #pragma unroll
    for (int kc = 0; kc < KC; ++kc) {
        bh8 ah[MTW], am[MTW], al[MTW];
        #pragma unroll
        for (int mtw = 0; mtw < MTW; ++mtw) {
            const int off = ((kc * MT + mtoff + mtw) * 4 + q) * 128 + m * 8;
            ah[mtw] = *(const bh8*)(Ap + off);
            am[mtw] = *(const bh8*)(Ap + APL + off);
            al[mtw] = *(const bh8*)(Ap + 2 * APL + off);
        }
        #pragma unroll
        for (int nl = 0; nl < NTW; ++nl) {
            const int fo = ((kc * 16 + ntoff + nl) * 64 + lane) * 8;
            const bh8 bh = *(const bh8*)(Wp + fo);
            const bh8 bm = *(const bh8*)(Wp + WPL + fo);
            const bh8 bl = *(const bh8*)(Wp + 2 * WPL + fo);
            #pragma unroll
            for (int mtw = 0; mtw < MTW; ++mtw) {
                acc[mtw][nl] = __builtin_amdgcn_mfma_f32_16x16x32_bf16(ah[mtw], bl, acc[mtw][nl], 0, 0, 0);
                acc[mtw][nl] = __builtin_amdgcn_mfma_f32_16x16x32_bf16(am[mtw], bm, acc[mtw][nl], 0, 0, 0);
                acc[mtw][nl] = __builtin_amdgcn_mfma_f32_16x16x32_bf16(al[mtw], bh, acc[mtw][nl], 0, 0, 0);
                acc[mtw][nl] = __builtin_amdgcn_mfma_f32_16x16x32_bf16(ah[mtw], bm, acc[mtw][nl], 0, 0, 0);
                acc[mtw][nl] = __builtin_amdgcn_mfma_f32_16x16x32_bf16(am[mtw], bh, acc[mtw][nl], 0, 0, 0);
                acc[mtw][nl] = __builtin_amdgcn_mfma_f32_16x16x32_bf16(ah[mtw], bh, acc[mtw][nl], 0, 0, 0);
            }
        }
    }
}

// ---------------------------------------------------------------------------
// Fused weight prep: one launch does all 6 preps + counts zeroing.
// Block segments: [0,1024) expert | [1024,1040) Ws1 | [1040,1058) Wc1 |
// [1058,1066) W1(3pl) | [1066,1098) W2(2pl) | [1098,1106) gate | 1106 counts.
// ---------------------------------------------------------------------------
__global__ void prep_all(const float* __restrict__ We, ush* __restrict__ EWp,
                         const float* __restrict__ Ws1, ush* __restrict__ Ws1p,
                         const float* __restrict__ Wc1, ush* __restrict__ Wc1p,
                         const float* __restrict__ W1, ush* __restrict__ W1p,
                         const float* __restrict__ W2, ush* __restrict__ W2p2,
                         const float* __restrict__ b2,
                         const float* __restrict__ Wg, const float* __restrict__ bg,
                         float* __restrict__ Wg2, float* __restrict__ bg2,
                         int* __restrict__ counts)
{
    const int blk = blockIdx.x;
    if (blk < 1024) {                       // expert weights, 2-plane
        const int gid = blk * 256 + threadIdx.x;
        const int nn = gid & 15, nt = (gid >> 4) & 15, qd = (gid >> 8) & 3;
        const int kc = (gid >> 10) & 7, el = gid >> 13;
        const int n = nt * 16 + nn;
        const float* src = We + (size_t)el * 65536 + (size_t)(kc * 32 + qd * 8) * 256 + n;
        union { ush u[8]; bh8 v; } H, L;
        #pragma unroll
        for (int j = 0; j < 8; ++j) bfsplit(src[j * 256], H.u[j], L.u[j]);
        ush* d = EWp + (size_t)el * 131072 + (size_t)((kc * 16 + nt) * 64 + qd * 16 + nn) * 8;
        *(bh8*)d = H.v;
        *(bh8*)(d + 65536) = L.v;
    } else if (blk < 1058) {                // head weights, 2-plane
        const int isC = blk >= 1040;
        const int gid = (isC ? blk - 1040 : blk - 1024) * 256 + threadIdx.x;
        const int KC = isC ? 9 : 8, Kreal = isC ? 283 : 256;
        if (gid >= KC * 512) return;
        const float* W = isC ? Wc1 : Ws1;
        ush* dst = isC ? Wc1p : Ws1p;
        const int nn = gid & 15, nt = (gid >> 4) & 7, qd = (gid >> 7) & 3, kc = gid >> 9;
        const int n = nt * 16 + nn;
        union { ush u[8]; bh8 v; } H, L;
        #pragma unroll
        for (int j = 0; j < 8; ++j) {
            const int k = kc * 32 + qd * 8 + j;
            const float x = (k < Kreal) ? W[k * 128 + n] : 0.f;
            bfsplit(x, H.u[j], L.u[j]);
        }
        ush* d = dst + (size_t)((kc * 8 + nt) * 64 + qd * 16 + nn) * 8;
        *(bh8*)d = H.v;
        *(bh8*)(d + KC * 4096) = L.v;
    } else if (blk < 1066) {                // trunk W1, 3-plane
        const int gid = (blk - 1058) * 256 + threadIdx.x;
        const int KC = 2, Kreal = 63;
        const int n15 = gid & 15, qd = (gid >> 4) & 3, nt = (gid >> 6) & 15, kc = gid >> 10;
        const int n = nt * 16 + n15;
        const int plane = KC * 8192;
        union { ush u[8]; bh8 v; } H, M, L;
        #pragma unroll
        for (int j = 0; j < 8; ++j) {
            const int k = kc * 32 + qd * 8 + j;
            const float x = (k < Kreal) ? W1[k * 256 + n] : 0.f;
            bfsplit3(x, H.u[j], M.u[j], L.u[j]);
        }
        ush* d = W1p + (size_t)gid * 8;
        *(bh8*)d = H.v;
        *(bh8*)(d + plane) = M.v;
        *(bh8*)(d + 2 * plane) = L.v;
    } else if (blk < 1098) {                // trunk W2, 2-plane
        const int gid = (blk - 1066) * 256 + threadIdx.x;
        const int KC = 8;
        const int n15 = gid & 15, qd = (gid >> 4) & 3, nt = (gid >> 6) & 15, kc = gid >> 10;
        const int n = nt * 16 + n15;
        const int plane = KC * 8192;
        union { ush u[8]; bh8 v; } H, L;
        #pragma unroll
        for (int j = 0; j < 8; ++j) {
            const int k = kc * 32 + qd * 8 + j;
            bfsplit(W2[k * 256 + n], H.u[j], L.u[j]);
        }
        ush* d = W2p2 + (size_t)gid * 8;
        *(bh8*)d = H.v;
        *(bh8*)(d + plane) = L.v;
    } else if (blk < 1106) {                // fused gate: Wg2 = W2@Wg, bg2
        const int gid = (blk - 1098) * 256 + threadIdx.x;
        const int k = gid >> 3, e = gid & 7;
        float s = 0.f;
        for (int j = 0; j < HD; ++j) s += W2[k * HD + j] * Wg[j * NE + e];
        Wg2[k * NE + e] = s;
        if (gid < NE) {
            float t = bg[gid];
            for (int j = 0; j < HD; ++j) t += b2[j] * Wg[j * NE + gid];
            bg2[gid] = t;
        }
    } else {                                // counts zeroing
        if (threadIdx.x < NE) counts[threadIdx.x] = 0;
    }
}

// ---------------------------------------------------------------------------
// Kernel 1: posenc -> l1 (3-plane 6-term) -> l2 (2-plane 3-term) -> fused gate
// + bucket. 32 rows/block, 512 thr (8 waves all-M, NTW=2). 2 blocks/CU.
// (proven R8/R11 config)
// ---------------------------------------------------------------------------
__global__ __launch_bounds__(512, 4) void trunk_kernel(
    const float* __restrict__ xyz,
    const ush* __restrict__ W1p, const float* __restrict__ b1,
    const ush* __restrict__ W2p2, const float* __restrict__ b2,
    const float* __restrict__ Wg2, const float* __restrict__ bg2,
    unsigned* __restrict__ h2p, float* __restrict__ gateout,
    int* __restrict__ counts, int* __restrict__ bucket)
{
    __shared__ ush   exP[3 * 2048];   // posenc 3 planes (KC=2, MT=2); later gate partials
    __shared__ ush   h1h[8192];       // h1 hi plane (KC=8, MT=2)
    __shared__ ush   h1l[8192];       // h1 lo plane
    __shared__ float h1f[32 * 259];   // h1 fp32 (gate path)
    __shared__ int   lcount[NE], lbase[NE], lpos[32], lexp[32];

    const int tid  = threadIdx.x;
    const int row0 = blockIdx.x * 32;
    if (tid < NE) lcount[tid] = 0;

    {   // posenc: thread (row, g) writes 4 k's
        const int row = tid & 31, g = tid >> 5;
        const int i = row0 + row;
        const float xv[3] = {xyz[3 * i], xyz[3 * i + 1], xyz[3 * i + 2]};
        const int mt = row >> 4, m = row & 15;
        #pragma unroll
        for (int kk = 0; kk < 4; ++kk) {
            const int k = g * 4 + kk;
            float v = 0.f;
            if (k < 3) v = xv[k];
            else if (k < 63) {
                const int l = (k - 3) / 6, c = (k - 3) % 6;
                const float f = (float)(1 << l);
                v = (c < 3) ? sinf(f * xv[c]) : cosf(f * xv[c - 3]);
            }
            const int kc = k >> 5, qq = (k >> 3) & 3, j = k & 7;
            const int off = ((kc * 2 + mt) * 4 + qq) * 128 + m * 8 + j;
            ush hh, mm, ll; split3t(v, hh, mm, ll);
            exP[off] = hh; exP[2048 + off] = mm; exP[4096 + off] = ll;
        }
    }
    __syncthreads();

    const int lane = tid & 63, wv = tid >> 6;
    const int q = lane >> 4, n15 = lane & 15;

    // --- l1 = relu(ex @ W1 + b1): 6-term; store fp32 (gate) + 2-plane (l2) ---
    {
        f4 acc[2][2];
        #pragma unroll
        for (int a = 0; a < 2; ++a)
            #pragma unroll
            for (int b_ = 0; b_ < 2; ++b_) acc[a][b_] = (f4){0.f, 0.f, 0.f, 0.f};
        gemm3<2, 2, 2, 2>(exP, W1p, lane, 0, wv * 2, acc);
        #pragma unroll
        for (int nl = 0; nl < 2; ++nl) {
            const int col = wv * 32 + nl * 16 + n15;
            const float bias = b1[col];
            const int kc = col >> 5, qc = (col >> 3) & 3, jc = col & 7;
            #pragma unroll
            for (int mt = 0; mt < 2; ++mt)
                #pragma unroll
                for (int r = 0; r < 4; ++r) {
                    const int row = mt * 16 + q * 4 + r;
                    const float v = fmaxf(acc[mt][nl][r] + bias, 0.f);
                    const int off = ((kc * 2 + mt) * 4 + qc) * 128 + (q * 4 + r) * 8 + jc;
                    ush hh, ll; split2t(v, hh, ll);
                    h1h[off] = hh; h1l[off] = ll;
                    h1f[row * 259 + col] = v;
                }
        }
    }
    __syncthreads();

    // --- l2 = h1 @ W2 + b2: 2-plane 3-term; epilogue straight to global ---
    {
        f4 acc[2][2];
        #pragma unroll
        for (int a = 0; a < 2; ++a)
            #pragma unroll
            for (int b_ = 0; b_ < 2; ++b_) acc[a][b_] = (f4){0.f, 0.f, 0.f, 0.f};
        gemm2p<8, 2, 16, 2, 2>(h1h, h1l, W2p2, W2p2 + 65536, lane, 0, wv * 2, acc);
        __syncthreads();   // all h1h/h1l reads done before part overlay
        #pragma unroll
        for (int nl = 0; nl < 2; ++nl) {
            const int col = wv * 32 + nl * 16 + n15;
            const float bias = b2[col];
            #pragma unroll
            for (int mt = 0; mt < 2; ++mt)
                #pragma unroll
                for (int r = 0; r < 4; ++r) {
                    const int row = mt * 16 + q * 4 + r;
                    h2p[(size_t)(row0 + row) * HD + col] = pack2t(acc[mt][nl][r] + bias);
                }
        }
    }

    // --- gate partials from h1f via fused Wg2 (h1f stable; exP dead) ---
    float* part = (float*)exP;        // [8][32][8]
    if (tid < 256) {
        const int row = tid & 31, seg = tid >> 5, k0 = seg * 32;
        float lg[NE];
        #pragma unroll
        for (int e = 0; e < NE; ++e) lg[e] = 0.f;
        for (int k = k0; k < k0 + 32; ++k) {
            const float hv = h1f[row * 259 + k];
            const float4 w0 = *(const float4*)(Wg2 + k * 8);
            const float4 w1 = *(const float4*)(Wg2 + k * 8 + 4);
            lg[0] = fmaf(hv, w0.x, lg[0]); lg[1] = fmaf(hv, w0.y, lg[1]);
            lg[2] = fmaf(hv, w0.z, lg[2]); lg[3] = fmaf(hv, w0.w, lg[3]);
            lg[4] = fmaf(hv, w1.x, lg[4]); lg[5] = fmaf(hv, w1.y, lg[5]);
            lg[6] = fmaf(hv, w1.z, lg[6]); lg[7] = fmaf(hv, w1.w, lg[7]);
        }
        #pragma unroll
        for (int e = 0; e < NE; ++e) part[(seg * 32 + row) * 8 + e] = lg[e];
    }
    __syncthreads();

    if (tid < 32) {
        float lg[NE];
        #pragma unroll
        for (int e = 0; e < NE; ++e) {
            float s = bg2[e];
            #pragma unroll
            for (int sg = 0; sg < 8; ++sg) s += part[(sg * 32 + tid) * 8 + e];
            lg[e] = s;
        }
        int best = 0; float mx = lg[0];
        #pragma unroll
        for (int e = 1; e < NE; ++e) if (lg[e] > mx) { mx = lg[e]; best = e; }
        float s = 0.f;
        #pragma unroll
        for (int e = 0; e < NE; ++e) s += expf(lg[e] - mx);
        gateout[row0 + tid] = 1.f / s;
        lexp[tid] = best;
        lpos[tid] = atomicAdd(&lcount[best], 1);
    }
    __syncthreads();
    if (tid < NE) lbase[tid] = atomicAdd(&counts[tid], lcount[tid]);
    __syncthreads();
    if (tid < 32) {
        const int e = lexp[tid];
        bucket[e * NS + lbase[e] + lpos[tid]] = row0 + tid;
    }
}

// ---------------------------------------------------------------------------
// Kernel 2: expert MLP + heads (proven shape: 64 rows, 8 waves all-M MT=4,
// NTW=2; B loaded once per block). LDS 78KB -> 2 blocks/CU.
// ---------------------------------------------------------------------------
__global__ __launch_bounds__(512, 4) void expert_kernel(
    const unsigned* __restrict__ h2p, const float* __restrict__ gatebuf,
    const int* __restrict__ counts, const int* __restrict__ bucket,
    const ush* __restrict__ EWp, const float* __restrict__ be,
    const float* __restrict__ dirs,
    const ush* __restrict__ Ws1p, const float* __restrict__ bs1,
    const float* __restrict__ Ws2, const float* __restrict__ bs2,
    const ush* __restrict__ Wc1p, const float* __restrict__ bc1,
    const float* __restrict__ Wc2, const float* __restrict__ bc2,
    float* __restrict__ outp)
{
    __shared__ ush   Ah[9 * 2048];      // hi plane (KC=9 incl. dirs ext); later fp32 s
    __shared__ ush   Al[9 * 2048];      // lo plane;                       later fp32 c
    __shared__ float dotp[4 * 64 * 4];
    __shared__ int   idx[64];
    __shared__ float gatev[64];

    const int tid = threadIdx.x;
    const int e   = blockIdx.x >> 10;
    const int t   = blockIdx.x & 1023;
    const int cnt = counts[e];
    if (t * 64 >= cnt) return;
    const int nact = min(64, cnt - t * 64);

    if (tid < 64) {
        const int src = bucket[e * NS + t * 64 + min(tid, nact - 1)];
        idx[tid]   = src;
        gatev[tid] = gatebuf[src];
    }
    __syncthreads();

    const int lane = tid & 63, wv = tid >> 6;
    const int q = lane >> 4, n15 = lane & 15;

    {   // gather: wave wv -> kc=wv, lane = row; unpack packed h2 into planes
        const int row = lane, mt = row >> 4, m = row & 15;
        const unsigned* src = h2p + (size_t)idx[row] * HD + wv * 32;
        #pragma unroll
        for (int sub = 0; sub < 4; ++sub) {
            bh8 hv, lv;
            unpack8(src + sub * 8, hv, lv);
            const int off = ((wv * 4 + mt) * 4 + sub) * 128 + m * 8;
            *(bh8*)(Ah + off) = hv;
            *(bh8*)(Al + off) = lv;
        }
    }
    if (tid < 64) {   // dirs posenc ext -> kc=8 region
        const int row = tid, i = idx[row];
        const int mt = row >> 4, m = row & 15;
        const float d0 = dirs[3 * i], d1 = dirs[3 * i + 1], d2 = dirs[3 * i + 2];
        float vals[32];
        vals[0] = d0; vals[1] = d1; vals[2] = d2;
        float f = 1.f;
        #pragma unroll
        for (int l = 0; l < 4; ++l) {
            vals[3 + 6 * l + 0] = sinf(f * d0);
            vals[3 + 6 * l + 1] = sinf(f * d1);
            vals[3 + 6 * l + 2] = sinf(f * d2);
            vals[3 + 6 * l + 3] = cosf(f * d0);
            vals[3 + 6 * l + 4] = cosf(f * d1);
            vals[3 + 6 * l + 5] = cosf(f * d2);
            f *= 2.f;
        }
        #pragma unroll
        for (int c = 27; c < 32; ++c) vals[c] = 0.f;
        #pragma unroll
        for (int k2 = 0; k2 < 32; ++k2) {
            const int off = ((8 * 4 + mt) * 4 + (k2 >> 3)) * 128 + m * 8 + (k2 & 7);
            ush hh, ll; split2t(vals[k2], hh, ll);
            Ah[off] = hh; Al[off] = ll;
        }
    }
    __syncthreads();

    const float* bb = be + e * 4 * HD;
    const ush* W0 = EWp + (size_t)(e * 4) * 131072;

    // ---- l0: A <- relu(A @ W0 + b0) ----
    {
        f4 acc[4][2];
        #pragma unroll
        for (int mt = 0; mt < 4; ++mt)
            #pragma unroll
            for (int nl = 0; nl < 2; ++nl) acc[mt][nl] = (f4){0.f, 0.f, 0.f, 0.f};
        gemm2p<8, 2, 16, 4, 4>(Ah, Al, W0, W0 + 65536, lane, 0, wv * 2, acc);
        __syncthreads();
        #pragma unroll
        for (int nl = 0; nl < 2; ++nl) {
            const int col = wv * 32 + nl * 16 + n15;
            const float bias = bb[col];
            const int kc = col >> 5, qc = (col >> 3) & 3, jc = col & 7;
            #pragma unroll
            for (int mt = 0; mt < 4; ++mt)
                #pragma unroll
                for (int r = 0; r < 4; ++r) {
                    const int off = ((kc * 4 + mt) * 4 + qc) * 128 + (q * 4 + r) * 8 + jc;
                    const float v = fmaxf(acc[mt][nl][r] + bias, 0.f);
                    ush hh, ll; split2t(v, hh, ll);
                    Ah[off] = hh; Al[off] = ll;
                }
        }
        __syncthreads();
    }
    // ---- l1: A <- relu(A @ W1 + b1 + skip)   (skip re-read from L2-hot h2p) ----
    {
        f4 acc[4][2];
        #pragma unroll
        for (int mt = 0; mt < 4; ++mt)
            #pragma unroll
            for (int nl = 0; nl < 2; ++nl) acc[mt][nl] = (f4){0.f, 0.f, 0.f, 0.f};
        gemm2p<8, 2, 16, 4, 4>(Ah, Al, W0 + 131072, W0 + 131072 + 65536, lane, 0, wv * 2, acc);
        __syncthreads();
        #pragma unroll
        for (int nl = 0; nl < 2; ++nl) {
            const int col = wv * 32 + nl * 16 + n15;
            const float bias = bb[256 + col];
            const int kc = col >> 5, qc = (col >> 3) & 3, jc = col & 7;
            #pragma unroll
            for (int mt = 0; mt < 4; ++mt)
                #pragma unroll
                for (int r = 0; r < 4; ++r) {
                    const int row = mt * 16 + q * 4 + r;
                    const int off = ((kc * 4 + mt) * 4 + qc) * 128 + (q * 4 + r) * 8 + jc;
                    const float sk = unpackf(h2p[(size_t)idx[row] * HD + col]);
                    const float v = fmaxf(acc[mt][nl][r] + bias + sk, 0.f);
                    ush hh, ll; split2t(v, hh, ll);
                    Ah[off] = hh; Al[off] = ll;
                }
        }
        __syncthreads();
    }
    // ---- l2: A <- relu(A @ W2 + b2) ----
    {
        f4 acc[4][2];
        #pragma unroll
        for (int mt = 0; mt < 4; ++mt)
            #pragma unroll
            for (int nl = 0; nl < 2; ++nl) acc[mt][nl] = (f4){0.f, 0.f, 0.f, 0.f};
        gemm2p<8, 2, 16, 4, 4>(Ah, Al, W0 + 2 * 131072, W0 + 2 * 131072 + 65536, lane, 0, wv * 2, acc);
        __syncthreads();
        #pragma unroll
        for (int nl = 0; nl < 2; ++nl) {
            const int col = wv * 32 + nl * 16 + n15;
            const float bias = bb[512 + col];
            const int kc = col >> 5, qc = (col >> 3) & 3, jc = col & 7;
            #pragma unroll
            for (int mt = 0; mt < 4; ++mt)
                #pragma unroll
                for (int r = 0; r < 4; ++r) {
                    const int off = ((kc * 4 + mt) * 4 + qc) * 128 + (q * 4 + r) * 8 + jc;
                    const float v = fmaxf(acc[mt][nl][r] + bias, 0.f);
                    ush hh, ll; split2t(v, hh, ll);
                    Ah[off] = hh; Al[off] = ll;
                }
        }
        __syncthreads();
    }
    // ---- l3: A <- gate * (A @ W3 + b3)  (no relu) ----
    {
        f4 acc[4][2];
        #pragma unroll
        for (int mt = 0; mt < 4; ++mt)
            #pragma unroll
            for (int nl = 0; nl < 2; ++nl) acc[mt][nl] = (f4){0.f, 0.f, 0.f, 0.f};
        gemm2p<8, 2, 16, 4, 4>(Ah, Al, W0 + 3 * 131072, W0 + 3 * 131072 + 65536, lane, 0, wv * 2, acc);
        __syncthreads();
        #pragma unroll
        for (int nl = 0; nl < 2; ++nl) {
            const int col = wv * 32 + nl * 16 + n15;
            const float bias = bb[768 + col];
            const int kc = col >> 5, qc = (col >> 3) & 3, jc = col & 7;
            #pragma unroll
            for (int mt = 0; mt < 4; ++mt)
                #pragma unroll
                for (int r = 0; r < 4; ++r) {
                    const int row = mt * 16 + q * 4 + r;
                    const int off = ((kc * 4 + mt) * 4 + qc) * 128 + (q * 4 + r) * 8 + jc;
                    const float v = gatev[row] * (acc[mt][nl][r] + bias);
                    ush hh, ll; split2t(v, hh, ll);
                    Ah[off] = hh; Al[off] = ll;
                }
        }
        __syncthreads();
    }

    // ---- heads: s = relu(out@Ws1+bs1), c = relu([out,ed]@Wc1+bc1) ----
    {
        f4 sacc[4][1], cacc[4][1];
        #pragma unroll
        for (int mt = 0; mt < 4; ++mt) {
            sacc[mt][0] = (f4){0.f, 0.f, 0.f, 0.f};
            cacc[mt][0] = (f4){0.f, 0.f, 0.f, 0.f};
        }
        gemm2p<8, 1, 8, 4, 4>(Ah, Al, Ws1p, Ws1p + 32768, lane, 0, wv, sacc);
        gemm2p<9, 1, 8, 4, 4>(Ah, Al, Wc1p, Wc1p + 36864, lane, 0, wv, cacc);
        __syncthreads();
        float* sp = (float*)Ah;          // [64][133]
        float* cp = (float*)Al;
        const int col = wv * 16 + n15;
        const float b_s = bs1[col], b_c = bc1[col];
        #pragma unroll
        for (int mt = 0; mt < 4; ++mt)
            #pragma unroll
            for (int r = 0; r < 4; ++r) {
                const int row = mt * 16 + q * 4 + r;
                sp[row * 133 + col] = fmaxf(sacc[mt][0][r] + b_s, 0.f);
                cp[row * 133 + col] = fmaxf(cacc[mt][0][r] + b_c, 0.f);
            }
        __syncthreads();
    }
    // ---- final dots: 4 segs x 64 rows, 32 k each ----
    if (tid < 256) {
        const float* sp = (const float*)Ah;
        const float* cp = (const float*)Al;
        const int row = tid & 63, seg = tid >> 6, k0 = seg * 32;
        float ps = 0.f, p0 = 0.f, p1 = 0.f, p2 = 0.f;
        for (int k = k0; k < k0 + 32; ++k) {
            ps = fmaf(sp[row * 133 + k], Ws2[k], ps);
            const float cv = cp[row * 133 + k];
            p0 = fmaf(cv, Wc2[3 * k + 0], p0);
            p1 = fmaf(cv, Wc2[3 * k + 1], p1);
            p2 = fmaf(cv, Wc2[3 * k + 2], p2);
        }
        *(float4*)&dotp[(seg * 64 + row) * 4] = make_float4(ps, p0, p1, p2);
    }
    __syncthreads();
    if (tid < nact) {
        float sg = bs2[0], r0 = bc2[0], r1 = bc2[1], r2 = bc2[2];
        #pragma unroll
        for (int s2 = 0; s2 < 4; ++s2) {
            const float4 pv = *(const float4*)&dotp[(s2 * 64 + tid) * 4];
            sg += pv.x; r0 += pv.y; r1 += pv.z; r2 += pv.w;
        }
        float4 o;
        o.x = 1.f / (1.f + expf(-r0));
        o.y = 1.f / (1.f + expf(-r1));
        o.z = 1.f / (1.f + expf(-r2));
        o.w = fmaxf(sg, 0.f) + log1pf(expf(-fabsf(sg)));
        *(float4*)&outp[(size_t)idx[tid] * 4] = o;
    }
}

// ---------------------------------------------------------------------------
extern "C" void kernel_launch(void* const* d_in, const int* in_sizes, int n_in,
                              void* d_out, int out_size, void* d_ws, size_t ws_size,
                              hipStream_t stream)
{
    const float* xyz  = (const float*)d_in[0];
    const float* dirs = (const float*)d_in[1];
    const float* W1   = (const float*)d_in[2];
    const float* b1   = (const float*)d_in[3];
    const float* W2   = (const float*)d_in[4];
    const float* b2   = (const float*)d_in[5];
    const float* Wg   = (const float*)d_in[6];
    const float* bg   = (const float*)d_in[7];
    const float* We   = (const float*)d_in[8];
    const float* be   = (const float*)d_in[9];
    const float* Ws1  = (const float*)d_in[10];
    const float* bs1  = (const float*)d_in[11];
    const float* Ws2  = (const float*)d_in[12];
    const float* bs2  = (const float*)d_in[13];
    const float* Wc1  = (const float*)d_in[14];
    const float* bc1  = (const float*)d_in[15];
    const float* Wc2  = (const float*)d_in[16];
    const float* bc2  = (const float*)d_in[17];
    float* out = (float*)d_out;

    char* ws = (char*)d_ws;
    unsigned* h2p     = (unsigned*)ws;                        // 64 MB packed h2
    float*    gatebuf = (float*)(ws + 67108864);              // 256 KB
    int*      counts  = (int*)(ws + 67371008);                // 1 KB (padded)
    int*      bucket  = (int*)(ws + 67372032);                // 2 MB
    ush*      EWp     = (ush*)(ws + 69469184);                // 8 MB expert frags
    ush*      Ws1p    = (ush*)(ws + 77857792);                // 128 KB
    ush*      Wc1p    = (ush*)(ws + 77988864);                // 144 KB
    ush*      W1p     = (ush*)(ws + 78136320);                // 96 KB  (3 planes)
    ush*      W2p2    = (ush*)(ws + 78234624);                // 256 KB (2 planes)
    float*    Wg2     = (float*)(ws + 78496768);              // 8 KB
    float*    bg2     = (float*)(ws + 78504960);              // 32 B

    prep_all<<<1107, 256, 0, stream>>>(We, EWp, Ws1, Ws1p, Wc1, Wc1p,
                                       W1, W1p, W2, W2p2, b2, Wg, bg,
                                       Wg2, bg2, counts);
    trunk_kernel<<<NS / 32, 512, 0, stream>>>(xyz, W1p, b1, W2p2, b2, Wg2, bg2,
                                              h2p, gatebuf, counts, bucket);
    expert_kernel<<<NE * 1024, 512, 0, stream>>>(h2p, gatebuf, counts, bucket,
                                                 EWp, be, dirs, Ws1p, bs1, Ws2, bs2,
                                                 Wc1p, bc1, Wc2, bc2, out);
}